// Round 4
// baseline (256.993 us; speedup 1.0000x reference)
//
#include <hip/hip_runtime.h>

// NarrativeClassificationLoss — v8: row-contiguous, 100%-occupancy main.
// R7 post-mortem of v7 (85us main): WRITE_SIZE 54.7MB (15x the 3.7MB of
// partials, ~107B/thread) => scratch spill from the manual 2-deep
// pipeline (VGPR 40->64 at the launch_bounds edge). Also column slices
// (512B segments @4KB stride) cap read BW at 1.8TB/s vs v4's fully
// row-contiguous 2.4TB/s. v8 therefore:
//  - blocks own 16 consecutive rows; BDIM=512 = 256 col-quad owners x 2
//    row-sets -> each iter reads 8KB contiguous, block sweeps 64KB span;
//  - 1024 blocks x 512 thr = 4 blocks/CU = 32 waves/CU (100% occ cap);
//  - NO manual pipeline (compiler schedules; VGPR <=64 via bounds(512,8));
//  - zero atomics: one LDS fold across row-sets, exclusive per-block
//    3459-float partial (14.2MB float4 stores, the v4-verified path);
//  - coalesced 16-group reduce + 1-block finalize; 3 dispatches, no memset.
//
// B=16384, N_NARR=128, N_SUB=1024, K=8, GAMMA=2, weights (1,1,0.5).

#define BDIM 512
#define NROWS 16384
#define NNARR 128
#define NSUB 1024

#define ROWS_PER_BLOCK 16
#define NBLOCKS (NROWS / ROWS_PER_BLOCK)   // 1024
#define ITERS (ROWS_PER_BLOCK / 2)         // 8 (2 rows per iter)

// per-block partial layout (floats)
#define PSUB   0        // [256 quads][As4|Cs4|ss4]
#define PNARR  3072     // [128 cols][An|Cn|ns]
#define PSC    3456     // {fn, fs, hier}
#define PUSED  3459
#define PSTRIDE 3472    // 16-float aligned

#define NGRP 16
#define TPG (NBLOCKS / NGRP)               // 64 tables per group

__device__ __forceinline__ void bce_pieces(float x, float& sp_p, float& sp_m, float& sig) {
    float a = fabsf(x);
    float e = __expf(-a);              // exp(-|x|) in (0,1]
    float l = __logf(1.0f + e);        // ~log1p(e); err ~1e-7, fine after /2M
    sp_p = fmaxf(x, 0.0f) + l;
    sp_m = sp_p - x;
    float inv = __builtin_amdgcn_rcpf(1.0f + e);
    sig = (x >= 0.0f) ? inv : e * inv;
}

__global__ __launch_bounds__(BDIM, 8) void ncl_main(
    const float* __restrict__ nlog, const float* __restrict__ slog,
    const int*   __restrict__ nlab, const int*   __restrict__ slab,
    float* __restrict__ P)
{
    __shared__ float lsub[256][12];    // row-set-1 partials, 12KB
    __shared__ float lnar[128][3];     // row-set-1 narr partials
    __shared__ float lsc[8][3];        // per-wave scalar partials

    const int t  = threadIdx.x;
    const int tc = t & 255;            // col-quad: sub cols 4tc..4tc+3
    const int rs = t >> 8;             // row-set 0/1
    const int nc = tc >> 1;            // narr col (group of 8 sub cols)
    const bool even = (tc & 1) == 0;

    const int r0 = blockIdx.x * ROWS_PER_BLOCK + rs;
    const float* sp = slog + (size_t)r0 * NSUB  + 4 * tc;
    const int*   yp = slab + (size_t)r0 * NSUB  + 4 * tc;
    const float* np = nlog + (size_t)r0 * NNARR + nc;
    const int*   mp = nlab + (size_t)r0 * NNARR + nc;

    float As[4] = {0,0,0,0}, Cs[4] = {0,0,0,0}, ssum[4] = {0,0,0,0};
    float An = 0.f, Cn = 0.f, ns = 0.f, fn = 0.f, fs = 0.f, hier = 0.f;

    #pragma unroll 4
    for (int i = 0; i < ITERS; ++i) {
        const size_t so = (size_t)(2 * i) * NSUB;
        const size_t no = (size_t)(2 * i) * NNARR;
        const float4 xs = *(const float4*)(sp + so);
        const int4   ys = *(const int4*)  (yp + so);
        const float  nx   = np[no];
        const float  posv = (float)mp[no];   // narr label == pos mask

        float nsp_p, nsp_m, nsig;
        bce_pieces(nx, nsp_p, nsp_m, nsig);

        const float xv[4] = {xs.x, xs.y, xs.z, xs.w};
        const float yv[4] = {(float)ys.x, (float)ys.y, (float)ys.z, (float)ys.w};
        float mymax = 0.0f;
        #pragma unroll
        for (int k = 0; k < 4; ++k) {
            float sp_p, sp_m, sig;
            bce_pieces(xv[k], sp_p, sp_m, sig);
            float y = yv[k];
            As[k]   += posv * y * sp_m;
            Cs[k]   += posv * (1.0f - y) * sp_p;
            ssum[k] += y;
            float om = 1.0f - sig;
            fs += om * om * y * (-sp_m);     // log_sigmoid(x) = -softplus(-x)
            mymax = fmaxf(mymax, sig);
        }
        // group of 8 sub cols = adjacent thread pair (t, t^1): same rs, same nc
        float gmax = fmaxf(mymax, __shfl_xor(mymax, 1, 64));
        if (even) {
            hier += fmaxf(gmax - nsig, 0.0f) * posv;
            An += posv * nsp_m;
            Cn += (1.0f - posv) * nsp_p;
            ns += posv;
            float om = 1.0f - nsig;
            fn += om * om * posv * (-nsp_m);
        }
    }

    // full-wave butterfly for the scalar partials
    #pragma unroll
    for (int m = 1; m <= 32; m <<= 1) {
        fn   += __shfl_xor(fn,   m, 64);
        fs   += __shfl_xor(fs,   m, 64);
        hier += __shfl_xor(hier, m, 64);
    }
    if ((t & 63) == 0) {
        const int w = t >> 6;
        lsc[w][0] = fn; lsc[w][1] = fs; lsc[w][2] = hier;
    }

    // fold row-set 1 into row-set 0 via LDS, then exclusive stores.
    if (rs == 1) {
        #pragma unroll
        for (int k = 0; k < 4; ++k) {
            lsub[tc][k]     = As[k];
            lsub[tc][4 + k] = Cs[k];
            lsub[tc][8 + k] = ssum[k];
        }
        if (even) { lnar[nc][0] = An; lnar[nc][1] = Cn; lnar[nc][2] = ns; }
    }
    __syncthreads();

    float* const Pb = P + (size_t)blockIdx.x * PSTRIDE;
    if (rs == 0) {
        float a[12];
        #pragma unroll
        for (int k = 0; k < 4; ++k) {
            a[k]     = As[k]   + lsub[tc][k];
            a[4 + k] = Cs[k]   + lsub[tc][4 + k];
            a[8 + k] = ssum[k] + lsub[tc][8 + k];
        }
        *(float4*)(Pb + PSUB + tc * 12 + 0) = make_float4(a[0], a[1], a[2],  a[3]);
        *(float4*)(Pb + PSUB + tc * 12 + 4) = make_float4(a[4], a[5], a[6],  a[7]);
        *(float4*)(Pb + PSUB + tc * 12 + 8) = make_float4(a[8], a[9], a[10], a[11]);
        if (even) {
            Pb[PNARR + nc * 3 + 0] = An + lnar[nc][0];
            Pb[PNARR + nc * 3 + 1] = Cn + lnar[nc][1];
            Pb[PNARR + nc * 3 + 2] = ns + lnar[nc][2];
        }
    }
    if (t == 0) {
        float a = 0.f, b = 0.f, c = 0.f;
        #pragma unroll
        for (int w = 0; w < 8; ++w) { a += lsc[w][0]; b += lsc[w][1]; c += lsc[w][2]; }
        Pb[PSC + 0] = a; Pb[PSC + 1] = b; Pb[PSC + 2] = c;
    }
}

// group-reduce: block (e-chunk, g) sums 64 tables; fully coalesced.
__global__ __launch_bounds__(256) void ncl_reduce1(const float* __restrict__ P,
                                                   float* __restrict__ tmp)
{
    const int e = blockIdx.x * 256 + threadIdx.x;
    if (e >= PUSED) return;
    const int g = blockIdx.y;
    float s = 0.f;
    #pragma unroll 4
    for (int i = 0; i < TPG; ++i)
        s += P[(size_t)(g * TPG + i) * PSTRIDE + e];
    tmp[(size_t)g * PSTRIDE + e] = s;
}

__global__ __launch_bounds__(1024) void ncl_finalize(const float* __restrict__ tmp,
                                                     float* __restrict__ out)
{
    __shared__ float sr[6][16];
    const int t = threadIdx.x;
    const float Bf = (float)NROWS;

    // sub column t: quad q = t>>2, elem k = t&3
    const int q = t >> 2, k = t & 3;
    float As = 0.f, Csv = 0.f, ss = 0.f;
    #pragma unroll
    for (int g = 0; g < NGRP; ++g) {
        const float* p = tmp + (size_t)g * PSTRIDE + PSUB + q * 12 + k;
        As  += p[0];
        Csv += p[4];
        ss  += p[8];
    }
    float spw = fminf(fmaxf((Bf - ss) / (ss + 1e-6f), 1.0f), 50.0f);
    float sub_part = spw * As + Csv;

    float narr_part = 0.f, valid_part = 0.f;
    if (t < NNARR) {
        float An = 0.f, Cn = 0.f, ns = 0.f;
        #pragma unroll
        for (int g = 0; g < NGRP; ++g) {
            const float* p = tmp + (size_t)g * PSTRIDE + PNARR + t * 3;
            An += p[0]; Cn += p[1]; ns += p[2];
        }
        float npw = fminf(fmaxf((Bf - ns) / (ns + 1e-6f), 1.0f), 50.0f);
        narr_part  = npw * An + Cn;
        valid_part = ns;
    }

    float fn_p = 0.f, fs_p = 0.f, hier_p = 0.f;
    if (t < NGRP) {
        const float* p = tmp + (size_t)t * PSTRIDE + PSC;
        fn_p = p[0]; fs_p = p[1]; hier_p = p[2];
    }

    #pragma unroll
    for (int off = 32; off; off >>= 1) {
        sub_part   += __shfl_down(sub_part,   off, 64);
        narr_part  += __shfl_down(narr_part,  off, 64);
        valid_part += __shfl_down(valid_part, off, 64);
        fn_p       += __shfl_down(fn_p,       off, 64);
        fs_p       += __shfl_down(fs_p,       off, 64);
        hier_p     += __shfl_down(hier_p,     off, 64);
    }
    if ((t & 63) == 0) {
        int w = t >> 6;
        sr[0][w] = sub_part; sr[1][w] = narr_part; sr[2][w] = valid_part;
        sr[3][w] = fn_p;     sr[4][w] = fs_p;      sr[5][w] = hier_p;
    }
    __syncthreads();
    if (t == 0) {
        float sub_tot = 0.f, narr_tot = 0.f, valid = 0.f;
        float fn = 0.f, fs = 0.f, hier = 0.f;
        #pragma unroll
        for (int i = 0; i < 16; ++i) {
            sub_tot += sr[0][i]; narr_tot += sr[1][i]; valid += sr[2][i];
            fn += sr[3][i]; fs += sr[4][i]; hier += sr[5][i];
        }

        float narrative_loss = narr_tot / (Bf * (float)NNARR);
        float sub_loss = (valid > 0.0f) ? (sub_tot * (1.0f / 8.0f)) / fmaxf(valid, 1.0f) : 0.0f;
        float nf = fn / (Bf * (float)NNARR);
        float sf = fs / (Bf * (float)NSUB);
        float hier_loss = hier / Bf;

        out[0] = (narrative_loss - 0.1f * nf)
               + (sub_loss       - 0.1f * sf)
               + 0.5f * hier_loss;
    }
}

extern "C" void kernel_launch(void* const* d_in, const int* in_sizes, int n_in,
                              void* d_out, int out_size, void* d_ws, size_t ws_size,
                              hipStream_t stream) {
    const float* nlog = (const float*)d_in[0];
    const float* slog = (const float*)d_in[1];
    const int*   nlab = (const int*)d_in[2];
    const int*   slab = (const int*)d_in[3];
    float* P   = (float*)d_ws;                        // 1024 * 3472 floats
    float* tmp = P + (size_t)NBLOCKS * PSTRIDE;       // 16 * 3472 floats
    float* out = (float*)d_out;

    // all workspace cells are exclusively written before read: no memset.
    ncl_main<<<NBLOCKS, BDIM, 0, stream>>>(nlog, slog, nlab, slab, P);
    dim3 gr((PUSED + 255) / 256, NGRP);
    ncl_reduce1<<<gr, 256, 0, stream>>>(P, tmp);
    ncl_finalize<<<1, 1024, 0, stream>>>(tmp, out);
}

// Round 5
// 186.321 us; speedup vs baseline: 1.3793x; 1.3793x over previous
//
#include <hip/hip_runtime.h>

// NarrativeClassificationLoss — v9: v4 structure, 2x grid, no reg pinch.
// R8 post-mortem of v8 (140us main): launch_bounds(512,8) capped VGPR at
// 64 -> compiler emitted 32-VGPR kernel that spills accumulators every
// iteration (WRITE_SIZE 279MB ~ 20x partials, FETCH 205MB). Confirmed
// rules: row-contiguous reads (v4/v8), zero atomics + exclusive stores
// (v4/v7), VGPR budget >= ~85 (v3/v7/v8 all spilled when pinched).
// v4's 62us main was grid-limited: 1024 blocks = 4/CU = 50% occ cap,
// latency-bound at 37% measured.
// v9: same two-phase v4 kernel, ROWS_PER_BLOCK 8 -> 2048 blocks x 256thr,
// launch_bounds(256,6): 6 blocks/CU (75% cap), VGPR budget ~84 (body
// needs ~60, no spill). Exclusive 3459-float tables (28.4MB), coalesced
// 32-chunk reduce + 1-block finalize; 3 dispatches, no memset, no atomics.
// Runtime ws_size check falls back to 16-row/1024-block template (14.6MB).
//
// B=16384, N_NARR=128, N_SUB=1024, K=8, GAMMA=2, weights (1,1,0.5).

#define BDIM 256
#define NROWS 16384
#define NNARR 128
#define NSUB 1024

// per-block table layout (floats)
#define WS_AN    0      // [128]  sum_b y*sp(-x)            (narrative)
#define WS_CN    128    // [128]  sum_b (1-y)*sp(x)
#define WS_NSUM  256    // [128]  col sums of narrative labels
#define WS_AS    384    // [1024] sum_b pos*y*sp(-x)        (subnarrative)
#define WS_CS    1408   // [1024] sum_b pos*(1-y)*sp(x)
#define WS_SSUM  2432   // [1024] col sums of sub labels
#define WS_FN    3456   // focal narrative sum
#define WS_FS    3457   // focal subnarrative sum
#define WS_HIER  3458   // hierarchy sum
#define WS_FLOATS 3459
#define CSTRIDE  3472   // table stride in floats (16B aligned)

#define NCHUNK 32       // reduce fan-in groups

__device__ __forceinline__ void bce_pieces(float x, float& sp_p, float& sp_m, float& sig) {
    float a = fabsf(x);
    float e = __expf(-a);              // exp(-|x|) in (0,1]
    float l = __logf(1.0f + e);        // ~log1p(e); err ~1e-7, fine after /2M
    sp_p = fmaxf(x, 0.0f) + l;
    sp_m = sp_p - x;
    float inv = __builtin_amdgcn_rcpf(1.0f + e);
    sig = (x >= 0.0f) ? inv : e * inv;
}

// RPB = rows per block (8 -> 2048 blocks, 16 -> 1024 blocks fallback).
template<int RPB>
__global__ __launch_bounds__(BDIM, 6) void ncl_main(
    const float* __restrict__ nlog, const float* __restrict__ slog,
    const int*   __restrict__ nlab, const int*   __restrict__ slab,
    float* __restrict__ P)
{
    __shared__ float sred[BDIM][13];   // narrative fold buffer (+1 pad)
    __shared__ float ssc[4][3];        // per-wave scalar partials

    const int t  = threadIdx.x;
    const int r0 = blockIdx.x * RPB;
    float* const Pb = P + (size_t)blockIdx.x * CSTRIDE;

    float fn = 0.f, fs = 0.f, hier = 0.f;

    // ---- narrative phase: RPB rows x 128 cols, fully coalesced float4 ----
    // iter i: quad q = i*256+t covers row q>>5, col-quad q&31.
    {
        float An[4] = {0,0,0,0}, Cn[4] = {0,0,0,0}, ns[4] = {0,0,0,0};
        #pragma unroll
        for (int i = 0; i < RPB / 8; ++i) {
            const int base = r0 * NNARR + 4 * (i * BDIM + t);
            const float4 xs = *(const float4*)(nlog + base);
            const int4   ys = *(const int4*)  (nlab + base);
            const float xv[4] = {xs.x, xs.y, xs.z, xs.w};
            const float yv[4] = {(float)ys.x, (float)ys.y, (float)ys.z, (float)ys.w};
            #pragma unroll
            for (int j = 0; j < 4; ++j) {
                float sp_p, sp_m, sig;
                bce_pieces(xv[j], sp_p, sp_m, sig);
                float y = yv[j];
                An[j] += y * sp_m;
                Cn[j] += (1.0f - y) * sp_p;
                ns[j] += y;
                float om = 1.0f - sig;
                fn += om * om * y * (-sp_m);   // log_sigmoid(x) = -softplus(-x)
            }
        }
        // fold: 8 threads (t, t+32, ..., t+224) share col-quad t&31
        #pragma unroll
        for (int j = 0; j < 4; ++j) {
            sred[t][j] = An[j]; sred[t][4 + j] = Cn[j]; sred[t][8 + j] = ns[j];
        }
    }
    __syncthreads();
    if (t < 32) {
        float a[12];
        #pragma unroll
        for (int j = 0; j < 12; ++j) a[j] = sred[t][j];
        #pragma unroll
        for (int s = 1; s < 8; ++s)
            #pragma unroll
            for (int j = 0; j < 12; ++j) a[j] += sred[t + 32 * s][j];
        *(float4*)(Pb + WS_AN   + 4 * t) = make_float4(a[0], a[1], a[2],  a[3]);
        *(float4*)(Pb + WS_CN   + 4 * t) = make_float4(a[4], a[5], a[6],  a[7]);
        *(float4*)(Pb + WS_NSUM + 4 * t) = make_float4(a[8], a[9], a[10], a[11]);
    }
    // sred not used again; ssc is a separate array -> no barrier needed here.

    // ---- sub phase: RPB rows; thread owns cols 4t..4t+3 (group g = t>>1) ----
    const int g = t >> 1;
    float As[4] = {0,0,0,0}, Cs[4] = {0,0,0,0}, ss[4] = {0,0,0,0};
    #pragma unroll 4
    for (int i = 0; i < RPB; ++i) {
        const int r = r0 + i;
        const float  nx   = nlog[r * NNARR + g];
        const float  posv = (float)nlab[r * NNARR + g];
        const float4 xs = *(const float4*)(slog + (size_t)r * NSUB + 4 * t);
        const int4   ys = *(const int4*)  (slab + (size_t)r * NSUB + 4 * t);

        float nsig;
        {
            float a = fabsf(nx);
            float e = __expf(-a);
            float inv = __builtin_amdgcn_rcpf(1.0f + e);
            nsig = (nx >= 0.0f) ? inv : e * inv;
        }

        const float xv[4] = {xs.x, xs.y, xs.z, xs.w};
        const float yv[4] = {(float)ys.x, (float)ys.y, (float)ys.z, (float)ys.w};
        float mymax = 0.0f;
        #pragma unroll
        for (int j = 0; j < 4; ++j) {
            float sp_p, sp_m, sig;
            bce_pieces(xv[j], sp_p, sp_m, sig);
            float y = yv[j];
            As[j] += posv * y * sp_m;
            Cs[j] += posv * (1.0f - y) * sp_p;
            ss[j] += y;
            float om = 1.0f - sig;
            fs += om * om * y * (-sp_m);
            mymax = fmaxf(mymax, sig);
        }
        // group max over 8 cols = adjacent lane pair
        float gmax = fmaxf(mymax, __shfl_xor(mymax, 1, 64));
        if ((t & 1) == 0)
            hier += fmaxf(gmax - nsig, 0.0f) * posv;
    }

    // thread t uniquely owns its 4 sub cols within the block: direct store
    *(float4*)(Pb + WS_AS   + 4 * t) = make_float4(As[0], As[1], As[2], As[3]);
    *(float4*)(Pb + WS_CS   + 4 * t) = make_float4(Cs[0], Cs[1], Cs[2], Cs[3]);
    *(float4*)(Pb + WS_SSUM + 4 * t) = make_float4(ss[0], ss[1], ss[2], ss[3]);

    // scalar partials: wave shuffle reduce -> LDS -> thread 0
    #pragma unroll
    for (int off = 32; off; off >>= 1) {
        fn   += __shfl_down(fn,   off, 64);
        fs   += __shfl_down(fs,   off, 64);
        hier += __shfl_down(hier, off, 64);
    }
    if ((t & 63) == 0) {
        int w = t >> 6;
        ssc[w][0] = fn; ssc[w][1] = fs; ssc[w][2] = hier;
    }
    __syncthreads();
    if (t == 0) {
        float a = 0.f, b = 0.f, c = 0.f;
        #pragma unroll
        for (int w = 0; w < 4; ++w) { a += ssc[w][0]; b += ssc[w][1]; c += ssc[w][2]; }
        Pb[WS_FN] = a; Pb[WS_FS] = b; Pb[WS_HIER] = c;
    }
}

// reduce: block (e-chunk, g) sums tpg tables -> tmp[g]; fully coalesced.
__global__ __launch_bounds__(256) void ncl_reduce1(const float* __restrict__ P,
                                                   float* __restrict__ tmp,
                                                   int tpg)
{
    const int e = blockIdx.x * 256 + threadIdx.x;
    if (e >= WS_FLOATS) return;
    const int g = blockIdx.y;
    const float* p = P + (size_t)g * tpg * CSTRIDE + e;
    float s = 0.f;
    #pragma unroll 4
    for (int i = 0; i < tpg; ++i)
        s += p[(size_t)i * CSTRIDE];
    tmp[(size_t)g * CSTRIDE + e] = s;
}

__global__ __launch_bounds__(1024) void ncl_finalize(const float* __restrict__ tmp,
                                                     float* __restrict__ out)
{
    __shared__ float sr[6][16];
    const int t = threadIdx.x;
    const float Bf = (float)NROWS;

    // sub column t, summed over the 32 chunk tables (coalesced across t)
    float As = 0.f, Csv = 0.f, ss = 0.f;
    #pragma unroll 4
    for (int gc = 0; gc < NCHUNK; ++gc) {
        const float* p = tmp + (size_t)gc * CSTRIDE;
        As  += p[WS_AS   + t];
        Csv += p[WS_CS   + t];
        ss  += p[WS_SSUM + t];
    }
    float spw = fminf(fmaxf((Bf - ss) / (ss + 1e-6f), 1.0f), 50.0f);
    float sub_part = spw * As + Csv;

    float narr_part = 0.f, valid_part = 0.f;
    if (t < NNARR) {
        float An = 0.f, Cn = 0.f, ns = 0.f;
        #pragma unroll 4
        for (int gc = 0; gc < NCHUNK; ++gc) {
            const float* p = tmp + (size_t)gc * CSTRIDE;
            An += p[WS_AN + t]; Cn += p[WS_CN + t]; ns += p[WS_NSUM + t];
        }
        float npw = fminf(fmaxf((Bf - ns) / (ns + 1e-6f), 1.0f), 50.0f);
        narr_part  = npw * An + Cn;
        valid_part = ns;
    }

    float fn_p = 0.f, fs_p = 0.f, hier_p = 0.f;
    if (t < NCHUNK) {
        const float* p = tmp + (size_t)t * CSTRIDE;
        fn_p = p[WS_FN]; fs_p = p[WS_FS]; hier_p = p[WS_HIER];
    }

    #pragma unroll
    for (int off = 32; off; off >>= 1) {
        sub_part   += __shfl_down(sub_part,   off, 64);
        narr_part  += __shfl_down(narr_part,  off, 64);
        valid_part += __shfl_down(valid_part, off, 64);
        fn_p       += __shfl_down(fn_p,       off, 64);
        fs_p       += __shfl_down(fs_p,       off, 64);
        hier_p     += __shfl_down(hier_p,     off, 64);
    }
    if ((t & 63) == 0) {
        int w = t >> 6;
        sr[0][w] = sub_part; sr[1][w] = narr_part; sr[2][w] = valid_part;
        sr[3][w] = fn_p;     sr[4][w] = fs_p;      sr[5][w] = hier_p;
    }
    __syncthreads();
    if (t == 0) {
        float sub_tot = 0.f, narr_tot = 0.f, valid = 0.f;
        float fn = 0.f, fs = 0.f, hier = 0.f;
        #pragma unroll
        for (int i = 0; i < 16; ++i) {
            sub_tot += sr[0][i]; narr_tot += sr[1][i]; valid += sr[2][i];
            fn += sr[3][i]; fs += sr[4][i]; hier += sr[5][i];
        }

        float narrative_loss = narr_tot / (Bf * (float)NNARR);
        float sub_loss = (valid > 0.0f) ? (sub_tot * (1.0f / 8.0f)) / fmaxf(valid, 1.0f) : 0.0f;
        float nf = fn / (Bf * (float)NNARR);
        float sf = fs / (Bf * (float)NSUB);
        float hier_loss = hier / Bf;

        out[0] = (narrative_loss - 0.1f * nf)
               + (sub_loss       - 0.1f * sf)
               + 0.5f * hier_loss;
    }
}

extern "C" void kernel_launch(void* const* d_in, const int* in_sizes, int n_in,
                              void* d_out, int out_size, void* d_ws, size_t ws_size,
                              hipStream_t stream) {
    const float* nlog = (const float*)d_in[0];
    const float* slog = (const float*)d_in[1];
    const int*   nlab = (const int*)d_in[2];
    const int*   slab = (const int*)d_in[3];
    float* P   = (float*)d_ws;
    float* out = (float*)d_out;

    const size_t availf = ws_size / 4;
    const bool big = availf >= (size_t)(2048 + NCHUNK) * CSTRIDE;
    const int nblocks = big ? 2048 : 1024;      // RPB 8 : 16
    float* tmp = P + (size_t)nblocks * CSTRIDE;
    const int tpg = nblocks / NCHUNK;

    // all workspace cells are exclusively written before read: no memset.
    if (big)
        ncl_main<8><<<2048, BDIM, 0, stream>>>(nlog, slog, nlab, slab, P);
    else
        ncl_main<16><<<1024, BDIM, 0, stream>>>(nlog, slog, nlab, slab, P);

    dim3 gr((WS_FLOATS + 255) / 256, NCHUNK);
    ncl_reduce1<<<gr, 256, 0, stream>>>(P, tmp, tpg);
    ncl_finalize<<<1, 1024, 0, stream>>>(tmp, out);
}